// Round 7
// baseline (280.011 us; speedup 1.0000x reference)
//
#include <hip/hip_runtime.h>
#include <math.h>

// Problem constants
#define NVOX  32768     // 32^3 up-res voxels
#define CIN   64
#define COUT  32
#define KT    27
#define CIT   1728      // CIN*KT
#define PSP   5832      // 18^3 padded half-res spatial

// Workspace layout (float offsets)
#define WS_XT   0                 // [5832][64] channel-last padded x (fp32)
#define WS_WA   373248            // bf16[216][32][8] deform-W A-frags (K tap-major)
#define WS_WO   400896            // bf16[216][96][8] offset-W A-frags (M padded 81->96)
#define WS_STAT 483840            // [32] sum, [32] sumsq

#define SST 584                   // S chunk row stride in u16 (1168 B)

typedef __attribute__((ext_vector_type(8))) short short8;
typedef __attribute__((ext_vector_type(4))) float floatx4;

static __device__ __forceinline__ unsigned short f2bf(float f) {
    unsigned int u = __float_as_uint(f);
    unsigned int r = (u + 0x7FFF + ((u >> 16) & 1)) >> 16;
    return (unsigned short)r;
}

// ---------------------------------------------------------------------------
// Merged prep (unchanged from R6).
// ---------------------------------------------------------------------------
__global__ void prep_all_kernel(const float* __restrict__ x,
                                const float* __restrict__ w_off,
                                const float* __restrict__ wmat,
                                float* __restrict__ ws) {
    int b = blockIdx.x, t = threadIdx.x;
    if (b < 5832) {
        int s = b, c = t;
        int qw = s % 18, qh = (s / 18) % 18, qd = s / 324;
        float v = 0.f;
        if (qd >= 1 && qd <= 16 && qh >= 1 && qh <= 16 && qw >= 1 && qw <= 16)
            v = x[((c * 16 + (qd - 1)) * 16 + (qh - 1)) * 16 + (qw - 1)];
        ws[WS_XT + s * 64 + c] = v;
    } else if (b < 5859) {
        unsigned short* wa = (unsigned short*)(ws + WS_WA);
        int idx4 = ((b - 5832) * 64 + t) * 4;
#pragma unroll
        for (int m = 0; m < 4; m++) {
            int idx = idx4 + m;                 // (kb, o)
            int kb = idx >> 5, o = idx & 31;
#pragma unroll
            for (int j = 0; j < 8; j++) {
                int kk = kb * 8 + j;            // K index, tap-major
                int tap = kk >> 6, ci = kk & 63;
                wa[idx * 8 + j] = f2bf(wmat[o * CIT + ci * 27 + tap]);
            }
        }
    } else if (b < 5940) {
        unsigned short* wo = (unsigned short*)(ws + WS_WO);
        int idx4 = ((b - 5859) * 64 + t) * 4;
#pragma unroll
        for (int mm = 0; mm < 4; mm++) {
            int idx = idx4 + mm;                // kb*96 + m
            int kb = idx / 96, m = idx % 96;
#pragma unroll
            for (int j = 0; j < 8; j++) {
                int kk = kb * 8 + j;
                int tap = kk >> 6, ci = kk & 63;
                float v = (m < 81) ? w_off[(m * 64 + ci) * 27 + tap] : 0.f;
                wo[idx * 8 + j] = f2bf(v);
            }
        }
    } else {
        ws[WS_STAT + t] = 0.f;
    }
}

// ---------------------------------------------------------------------------
// Fused offset-GEMM + deformable sample + deform-GEMM + BN stats.
// LDS 30.0 KB -> 5 blocks/CU:
//   smem  16x584 u16  (18688 B)  S chunks (both phases)
//   Plh   81x16 fp16  ( 2592 B)  offsets (phase0 out, phase1 in)
//   ubuf  9216 B overlay: phase0 reduce staging (6144) -> cba(4608)+cbw(4608)
//         -> epilogue pbuf (2048)  [disjoint lifetimes]
// Barriers: phase0 2/g, reduce 3, phase1 2/g (stage0(g) + MFMA(g-1) fused
// between barriers), epilogue 3.
// ---------------------------------------------------------------------------
__global__ __launch_bounds__(256, 5) void deform_kernel(
        const float* __restrict__ b_off, const float* __restrict__ bias,
        float* ws, float* __restrict__ out) {
    __shared__ __align__(16) unsigned short smem[16 * SST];   // 18688 B
    __shared__ __align__(16) _Float16 Plh[81 * 16];           // 2592 B
    __shared__ __align__(16) char ubuf[9216];
    __shared__ float rsum[COUT], rsq[COUT];

    float* red = (float*)ubuf;                 // 96*16 f32 (phase0 reduce)
    int*   cba = (int*)ubuf;                   // 144*8 int (phase1 coords)
    float* cbw = (float*)(ubuf + 4608);        // 144*8 f32 (phase1 weights)
    float* pbuf = (float*)ubuf;                // 512 f32 (epilogue)

    const float* xt = ws + WS_XT;
    const unsigned short* wa = (const unsigned short*)(ws + WS_WA);
    const unsigned short* wo = (const unsigned short*)(ws + WS_WO);
    float* gstat = ws + WS_STAT;

    int tid = threadIdx.x, wave = tid >> 6, lane = tid & 63;
    int pbase = blockIdx.x * 16;
    int d = pbase >> 10, h = (pbase >> 5) & 31, w0 = pbase & 31;

    if (tid < COUT) { rsum[tid] = 0.f; rsq[tid] = 0.f; }

    int mh = wave & 1, kh = wave >> 1;
    int col = lane & 15, quad = lane >> 4;

    // ================= Phase 0: offset GEMM =================
    floatx4 oacc0 = {0.f,0.f,0.f,0.f}, oacc1 = {0.f,0.f,0.f,0.f}, oacc2 = {0.f,0.f,0.f,0.f};
    const short8* wo8 = (const short8*)wo;
#pragma unroll 1
    for (int g = 0; g < 3; g++) {
        if (g) __syncthreads();             // prior MFMA0 smem reads done
        int rd = ((d + g - 1) >> 1) + 1;
#pragma unroll
        for (int vi = 0; vi < 4; vi++) {
            int v = wave * 4 + vi;
            int w = w0 + v;
            unsigned short* sb = smem + v * SST + lane;
#pragma unroll
            for (int tl = 0; tl < 9; tl++) {
                int kh2 = tl / 3, kw2 = tl % 3;
                int rh = ((h + kh2 - 1) >> 1) + 1;
                int rw = ((w + kw2 - 1) >> 1) + 1;
                int cell = (rd * 18 + rh) * 18 + rw;
                sb[tl * 64] = f2bf(xt[cell * 64 + lane]);
            }
        }
        __syncthreads();
#pragma unroll
        for (int s = 0; s < 9; s++) {
            int k_local = kh * 288 + s * 32;
            int kb = ((g * 576 + k_local) >> 3) + quad;
            short8 bfrag = *(const short8*)(smem + col * SST + k_local + quad * 8);
            short8 a0 = wo8[kb * 96 + mh * 48 + col];
            short8 a1 = wo8[kb * 96 + mh * 48 + 16 + col];
            short8 a2 = wo8[kb * 96 + mh * 48 + 32 + col];
            oacc0 = __builtin_amdgcn_mfma_f32_16x16x32_bf16(a0, bfrag, oacc0, 0, 0, 0);
            oacc1 = __builtin_amdgcn_mfma_f32_16x16x32_bf16(a1, bfrag, oacc1, 0, 0, 0);
            oacc2 = __builtin_amdgcn_mfma_f32_16x16x32_bf16(a2, bfrag, oacc2, 0, 0, 0);
        }
    }
    __syncthreads();
    if (kh == 1) {
#pragma unroll
        for (int r = 0; r < 4; r++) {
            red[(mh * 48 +      quad * 4 + r) * 16 + col] = oacc0[r];
            red[(mh * 48 + 16 + quad * 4 + r) * 16 + col] = oacc1[r];
            red[(mh * 48 + 32 + quad * 4 + r) * 16 + col] = oacc2[r];
        }
    }
    __syncthreads();
    if (kh == 0) {
#pragma unroll
        for (int r = 0; r < 4; r++) {
            int m0 = mh * 48 + quad * 4 + r;
            Plh[m0 * 16 + col] = (_Float16)(oacc0[r] + red[m0 * 16 + col] + b_off[m0]);
            int m1 = m0 + 16;
            Plh[m1 * 16 + col] = (_Float16)(oacc1[r] + red[m1 * 16 + col] + b_off[m1]);
            int m2 = m0 + 32;
            if (m2 < 81)
                Plh[m2 * 16 + col] = (_Float16)(oacc2[r] + red[m2 * 16 + col] + b_off[m2]);
        }
    }
    __syncthreads();    // Plh ready; red region free -> cba/cbw

    // ================= Phase 1: deform sample + GEMM =================
    int mt = wave & 1;
    floatx4 acc = {0.f, 0.f, 0.f, 0.f};
    const short8* wa8 = (const short8*)wa;

#pragma unroll 1
    for (int g = 0; g < 3; g++) {
        // ---- stage0(g): coord dedup (tid<144), + MFMA(g-1) back-to-back ----
        if (tid < 144) {
            int v = tid & 15, tl = tid >> 4;
            int tap = g * 9 + tl;
            int kh2 = tl / 3, kw2 = tl % 3;
            int w = w0 + v;
            float od = (float)Plh[(3 * tap + 0) * 16 + v];
            float oh = (float)Plh[(3 * tap + 1) * 16 + v];
            float ow = (float)Plh[(3 * tap + 2) * 16 + v];
            float pdc = (float)(d + g - 1) + od;
            float phc = (float)(h + kh2 - 1) + oh;
            float pwc = (float)(w + kw2 - 1) + ow;
            float fd0 = floorf(pdc), fh0 = floorf(phc), fw0 = floorf(pwc);
            float fd = pdc - fd0, fh = phc - fh0, fw = pwc - fw0;
            int id = (int)fd0, ih = (int)fh0, iw = (int)fw0;
            int rd0 = ((min(max(id,     -2), 33) >> 1) + 1) * (324 * 64);
            int rd1 = ((min(max(id + 1, -2), 33) >> 1) + 1) * (324 * 64);
            int rh0 = ((min(max(ih,     -2), 33) >> 1) + 1) * (18 * 64);
            int rh1 = ((min(max(ih + 1, -2), 33) >> 1) + 1) * (18 * 64);
            int rw0 = ((min(max(iw,     -2), 33) >> 1) + 1) * 64;
            int rw1 = ((min(max(iw + 1, -2), 33) >> 1) + 1) * 64;
            int* A = cba + tid * 8;
            float* W = cbw + tid * 8;
            A[0] = rd0 + rh0 + rw0; A[1] = rd0 + rh0 + rw1;
            A[2] = rd0 + rh1 + rw0; A[3] = rd0 + rh1 + rw1;
            A[4] = rd1 + rh0 + rw0; A[5] = rd1 + rh0 + rw1;
            A[6] = rd1 + rh1 + rw0; A[7] = rd1 + rh1 + rw1;
            float gd = 1.f - fd, gh = 1.f - fh, gw = 1.f - fw;
            W[0] = gd * gh * gw; W[1] = gd * gh * fw;
            W[2] = gd * fh * gw; W[3] = gd * fh * fw;
            W[4] = fd * gh * gw; W[5] = fd * gh * fw;
            W[6] = fd * fh * gw; W[7] = fd * fh * fw;
        }
        if (g) {
            // MFMA over PREVIOUS chunk (reads smem only; disjoint from cb)
#pragma unroll
            for (int s = 0; s < 9; s++) {
                int k_local = kh * 288 + s * 32;
                int kb = (((g - 1) * 576 + k_local) >> 3) + quad;
                short8 afrag = wa8[kb * 32 + mt * 16 + col];
                short8 bfrag = *(const short8*)(smem + col * SST + k_local + quad * 8);
                acc = __builtin_amdgcn_mfma_f32_16x16x32_bf16(afrag, bfrag, acc, 0, 0, 0);
            }
        }
        __syncthreads();   // cb ready; smem MFMA reads done

        // ---- gather(g): tap-outer / voxel-inner for 32-load batches ----
#pragma unroll 1
        for (int tl = 0; tl < 9; tl++) {
            int4 A0[4], A1[4];
            float4 W0[4], W1[4];
#pragma unroll
            for (int vi = 0; vi < 4; vi++) {
                int item = tl * 16 + wave * 4 + vi;
                const int4* a4 = (const int4*)(cba + item * 8);
                const float4* w4 = (const float4*)(cbw + item * 8);
                A0[vi] = a4[0]; A1[vi] = a4[1];
                W0[vi] = w4[0]; W1[vi] = w4[1];
            }
            float s0[4];
#pragma unroll
            for (int vi = 0; vi < 4; vi++) {
                s0[vi] = W0[vi].x * xt[A0[vi].x + lane] + W0[vi].y * xt[A0[vi].y + lane]
                       + W0[vi].z * xt[A0[vi].z + lane] + W0[vi].w * xt[A0[vi].w + lane]
                       + W1[vi].x * xt[A1[vi].x + lane] + W1[vi].y * xt[A1[vi].y + lane]
                       + W1[vi].z * xt[A1[vi].z + lane] + W1[vi].w * xt[A1[vi].w + lane];
            }
#pragma unroll
            for (int vi = 0; vi < 4; vi++)
                smem[(wave * 4 + vi) * SST + tl * 64 + lane] = f2bf(s0[vi]);
        }
        __syncthreads();   // S chunk ready
    }
    // MFMA over last chunk
#pragma unroll
    for (int s = 0; s < 9; s++) {
        int k_local = kh * 288 + s * 32;
        int kb = ((2 * 576 + k_local) >> 3) + quad;
        short8 afrag = wa8[kb * 32 + mt * 16 + col];
        short8 bfrag = *(const short8*)(smem + col * SST + k_local + quad * 8);
        acc = __builtin_amdgcn_mfma_f32_16x16x32_bf16(afrag, bfrag, acc, 0, 0, 0);
    }
    __syncthreads();       // cb region free -> pbuf

    if (kh == 1) {
#pragma unroll
        for (int r = 0; r < 4; r++) pbuf[mt * 256 + (quad * 4 + r) * 16 + col] = acc[r];
    }
    __syncthreads();
    if (kh == 0) {
#pragma unroll
        for (int r = 0; r < 4; r++) {
            int o = mt * 16 + quad * 4 + r;
            float val = acc[r] + pbuf[mt * 256 + (quad * 4 + r) * 16 + col] + bias[o];
            out[o * NVOX + pbase + col] = val;
            atomicAdd(&rsum[o], val);
            atomicAdd(&rsq[o], val * val);
        }
    }
    __syncthreads();
    if (tid < COUT) {
        atomicAdd(&gstat[tid], rsum[tid]);
        atomicAdd(&gstat[COUT + tid], rsq[tid]);
    }
}

// ---------------------------------------------------------------------------
// BN finalize + ReLU, in-place on d_out.
// ---------------------------------------------------------------------------
__global__ void bn_kernel(const float* __restrict__ ws,
                          const float* __restrict__ gamma,
                          const float* __restrict__ beta,
                          float* out) {
    int i = blockIdx.x * 256 + threadIdx.x;
    int o = i >> 15;
    const float* gstat = ws + WS_STAT;
    const float inv = 1.f / 32768.f;
    float mean = gstat[o] * inv;
    float var  = gstat[COUT + o] * inv - mean * mean;
    float sc   = rsqrtf(var + 1e-5f) * gamma[o];
    float v = (out[i] - mean) * sc + beta[o];
    out[i] = fmaxf(v, 0.f);
}

// ---------------------------------------------------------------------------
extern "C" void kernel_launch(void* const* d_in, const int* in_sizes, int n_in,
                              void* d_out, int out_size, void* d_ws, size_t ws_size,
                              hipStream_t stream) {
    const float* x     = (const float*)d_in[0];
    const float* w_off = (const float*)d_in[1];
    const float* b_off = (const float*)d_in[2];
    const float* wmat  = (const float*)d_in[3];
    const float* bias  = (const float*)d_in[4];
    const float* gamma = (const float*)d_in[5];
    const float* beta  = (const float*)d_in[6];
    float* ws  = (float*)d_ws;
    float* out = (float*)d_out;

    prep_all_kernel<<<5941, 64, 0, stream>>>(x, w_off, wmat, ws);
    deform_kernel<<<2048, 256, 0, stream>>>(b_off, bias, ws, out);
    bn_kernel<<<4096, 256, 0, stream>>>(ws, gamma, beta, out);
}

// Round 8
// 198.816 us; speedup vs baseline: 1.4084x; 1.4084x over previous
//
#include <hip/hip_runtime.h>
#include <math.h>

// Problem constants
#define NVOX  32768     // 32^3 up-res voxels
#define CIN   64
#define COUT  32
#define KT    27
#define CIT   1728      // CIN*KT
#define PSP   5832      // 18^3 padded half-res spatial

// Workspace layout (float offsets)
#define WS_XT   0                 // [5832][64] channel-last padded x (fp32)
#define WS_WA   373248            // bf16[216][32][8] deform-W A-frags (K tap-major)
#define WS_WO   400896            // bf16[216][96][8] offset-W A-frags (M padded 81->96)
#define WS_STAT 483840            // [32] sum, [32] sumsq

#define SST 584                   // S chunk row stride in u16 (1168 B)

typedef __attribute__((ext_vector_type(8))) short short8;
typedef __attribute__((ext_vector_type(4))) float floatx4;

static __device__ __forceinline__ unsigned short f2bf(float f) {
    unsigned int u = __float_as_uint(f);
    unsigned int r = (u + 0x7FFF + ((u >> 16) & 1)) >> 16;
    return (unsigned short)r;
}

// ---------------------------------------------------------------------------
// Merged prep (unchanged).
// ---------------------------------------------------------------------------
__global__ void prep_all_kernel(const float* __restrict__ x,
                                const float* __restrict__ w_off,
                                const float* __restrict__ wmat,
                                float* __restrict__ ws) {
    int b = blockIdx.x, t = threadIdx.x;
    if (b < 5832) {
        int s = b, c = t;
        int qw = s % 18, qh = (s / 18) % 18, qd = s / 324;
        float v = 0.f;
        if (qd >= 1 && qd <= 16 && qh >= 1 && qh <= 16 && qw >= 1 && qw <= 16)
            v = x[((c * 16 + (qd - 1)) * 16 + (qh - 1)) * 16 + (qw - 1)];
        ws[WS_XT + s * 64 + c] = v;
    } else if (b < 5859) {
        unsigned short* wa = (unsigned short*)(ws + WS_WA);
        int idx4 = ((b - 5832) * 64 + t) * 4;
#pragma unroll
        for (int m = 0; m < 4; m++) {
            int idx = idx4 + m;                 // (kb, o)
            int kb = idx >> 5, o = idx & 31;
#pragma unroll
            for (int j = 0; j < 8; j++) {
                int kk = kb * 8 + j;            // K index, tap-major
                int tap = kk >> 6, ci = kk & 63;
                wa[idx * 8 + j] = f2bf(wmat[o * CIT + ci * 27 + tap]);
            }
        }
    } else if (b < 5940) {
        unsigned short* wo = (unsigned short*)(ws + WS_WO);
        int idx4 = ((b - 5859) * 64 + t) * 4;
#pragma unroll
        for (int mm = 0; mm < 4; mm++) {
            int idx = idx4 + mm;                // kb*96 + m
            int kb = idx / 96, m = idx % 96;
#pragma unroll
            for (int j = 0; j < 8; j++) {
                int kk = kb * 8 + j;
                int tap = kk >> 6, ci = kk & 63;
                float v = (m < 81) ? w_off[(m * 64 + ci) * 27 + tap] : 0.f;
                wo[idx * 8 + j] = f2bf(v);
            }
        }
    } else {
        ws[WS_STAT + t] = 0.f;
    }
}

// ---------------------------------------------------------------------------
// Fused offset-GEMM + deformable sample + deform-GEMM + BN stats.
// R6 schedule (VGPR~56, VALUBusy 47%) + LDS diet -> 5 blocks/CU:
//   smem  16x584 u16 (18688 B)  S chunks
//   Plh   81x16 fp16 ( 2592 B)  offsets (phase0 out, phase1 in)
//   ubuf  9216 B overlay: phase0 red(6144) -> cba(4608)+cbw(4608) -> pbuf(2048)
// No min-waves clamp: let the allocator keep the gather pipelined.
// ---------------------------------------------------------------------------
__global__ __launch_bounds__(256) void deform_kernel(
        const float* __restrict__ b_off, const float* __restrict__ bias,
        float* ws, float* __restrict__ out) {
    __shared__ __align__(16) unsigned short smem[16 * SST];   // 18688 B
    __shared__ __align__(16) _Float16 Plh[81 * 16];           // 2592 B
    __shared__ __align__(16) char ubuf[9216];
    __shared__ float rsum[COUT], rsq[COUT];

    float* red  = (float*)ubuf;                // 96*16 f32 (phase0 reduce)
    int*   cba  = (int*)ubuf;                  // 144*8 int (phase1 coords)
    float* cbw  = (float*)(ubuf + 4608);       // 144*8 f32 (phase1 weights)
    float* pbuf = (float*)ubuf;                // 512 f32 (epilogue)

    const float* xt = ws + WS_XT;
    const unsigned short* wa = (const unsigned short*)(ws + WS_WA);
    const unsigned short* wo = (const unsigned short*)(ws + WS_WO);
    float* gstat = ws + WS_STAT;

    int tid = threadIdx.x, wave = tid >> 6, lane = tid & 63;
    int pbase = blockIdx.x * 16;
    int d = pbase >> 10, h = (pbase >> 5) & 31, w0 = pbase & 31;

    if (tid < COUT) { rsum[tid] = 0.f; rsq[tid] = 0.f; }

    int mh = wave & 1, kh = wave >> 1;
    int col = lane & 15, quad = lane >> 4;

    // ================= Phase 0: offset GEMM =================
    floatx4 oacc0 = {0.f,0.f,0.f,0.f}, oacc1 = {0.f,0.f,0.f,0.f}, oacc2 = {0.f,0.f,0.f,0.f};
    const short8* wo8 = (const short8*)wo;
#pragma unroll 1
    for (int g = 0; g < 3; g++) {
        if (g) __syncthreads();             // prior MFMA smem reads done
        int rd = ((d + g - 1) >> 1) + 1;
#pragma unroll
        for (int vi = 0; vi < 4; vi++) {
            int v = wave * 4 + vi;
            int w = w0 + v;
            unsigned short* sb = smem + v * SST + lane;
#pragma unroll
            for (int tl = 0; tl < 9; tl++) {
                int kh2 = tl / 3, kw2 = tl % 3;
                int rh = ((h + kh2 - 1) >> 1) + 1;
                int rw = ((w + kw2 - 1) >> 1) + 1;
                int cell = (rd * 18 + rh) * 18 + rw;
                sb[tl * 64] = f2bf(xt[cell * 64 + lane]);
            }
        }
        __syncthreads();
#pragma unroll
        for (int s = 0; s < 9; s++) {
            int k_local = kh * 288 + s * 32;
            int kb = ((g * 576 + k_local) >> 3) + quad;
            short8 bfrag = *(const short8*)(smem + col * SST + k_local + quad * 8);
            short8 a0 = wo8[kb * 96 + mh * 48 + col];
            short8 a1 = wo8[kb * 96 + mh * 48 + 16 + col];
            short8 a2 = wo8[kb * 96 + mh * 48 + 32 + col];
            oacc0 = __builtin_amdgcn_mfma_f32_16x16x32_bf16(a0, bfrag, oacc0, 0, 0, 0);
            oacc1 = __builtin_amdgcn_mfma_f32_16x16x32_bf16(a1, bfrag, oacc1, 0, 0, 0);
            oacc2 = __builtin_amdgcn_mfma_f32_16x16x32_bf16(a2, bfrag, oacc2, 0, 0, 0);
        }
    }
    __syncthreads();
    if (kh == 1) {
#pragma unroll
        for (int r = 0; r < 4; r++) {
            red[(mh * 48 +      quad * 4 + r) * 16 + col] = oacc0[r];
            red[(mh * 48 + 16 + quad * 4 + r) * 16 + col] = oacc1[r];
            red[(mh * 48 + 32 + quad * 4 + r) * 16 + col] = oacc2[r];
        }
    }
    __syncthreads();
    if (kh == 0) {
#pragma unroll
        for (int r = 0; r < 4; r++) {
            int m0 = mh * 48 + quad * 4 + r;
            Plh[m0 * 16 + col] = (_Float16)(oacc0[r] + red[m0 * 16 + col] + b_off[m0]);
            int m1 = m0 + 16;
            Plh[m1 * 16 + col] = (_Float16)(oacc1[r] + red[m1 * 16 + col] + b_off[m1]);
            int m2 = m0 + 32;
            if (m2 < 81)
                Plh[m2 * 16 + col] = (_Float16)(oacc2[r] + red[m2 * 16 + col] + b_off[m2]);
        }
    }
    // Plh ready after next sync (top of phase-1 loop); red then free -> cb

    // ================= Phase 1: deform sample + GEMM (R6 schedule) =========
    int mt = wave & 1;
    floatx4 acc = {0.f, 0.f, 0.f, 0.f};
    const short8* wa8 = (const short8*)wa;

#pragma unroll 1
    for (int g = 0; g < 3; g++) {
        __syncthreads();   // Plh ready (g=0) / prior gather+MFMA reads done
        if (tid < 144) {
            int v = tid & 15, tl = tid >> 4;
            int tap = g * 9 + tl;
            int kh2 = tl / 3, kw2 = tl % 3;
            int w = w0 + v;
            float od = (float)Plh[(3 * tap + 0) * 16 + v];
            float oh = (float)Plh[(3 * tap + 1) * 16 + v];
            float ow = (float)Plh[(3 * tap + 2) * 16 + v];
            float pdc = (float)(d + g - 1) + od;
            float phc = (float)(h + kh2 - 1) + oh;
            float pwc = (float)(w + kw2 - 1) + ow;
            float fd0 = floorf(pdc), fh0 = floorf(phc), fw0 = floorf(pwc);
            float fd = pdc - fd0, fh = phc - fh0, fw = pwc - fw0;
            int id = (int)fd0, ih = (int)fh0, iw = (int)fw0;
            int rd0 = ((min(max(id,     -2), 33) >> 1) + 1) * (324 * 64);
            int rd1 = ((min(max(id + 1, -2), 33) >> 1) + 1) * (324 * 64);
            int rh0 = ((min(max(ih,     -2), 33) >> 1) + 1) * (18 * 64);
            int rh1 = ((min(max(ih + 1, -2), 33) >> 1) + 1) * (18 * 64);
            int rw0 = ((min(max(iw,     -2), 33) >> 1) + 1) * 64;
            int rw1 = ((min(max(iw + 1, -2), 33) >> 1) + 1) * 64;
            int* A = cba + tid * 8;
            float* W = cbw + tid * 8;
            A[0] = rd0 + rh0 + rw0; A[1] = rd0 + rh0 + rw1;
            A[2] = rd0 + rh1 + rw0; A[3] = rd0 + rh1 + rw1;
            A[4] = rd1 + rh0 + rw0; A[5] = rd1 + rh0 + rw1;
            A[6] = rd1 + rh1 + rw0; A[7] = rd1 + rh1 + rw1;
            float gd = 1.f - fd, gh = 1.f - fh, gw = 1.f - fw;
            W[0] = gd * gh * gw; W[1] = gd * gh * fw;
            W[2] = gd * fh * gw; W[3] = gd * fh * fw;
            W[4] = fd * gh * gw; W[5] = fd * gh * fw;
            W[6] = fd * fh * gw; W[7] = fd * fh * fw;
        }
        __syncthreads();

        // Gather: S[v][tl*64 + lane] (bf16, conflict-free LDS writes)
#pragma unroll
        for (int vi = 0; vi < 4; vi++) {
            int v = wave * 4 + vi;
            unsigned short* sb = smem + v * SST + lane;
#pragma unroll
            for (int tl = 0; tl < 9; tl++) {
                int item = tl * 16 + v;
                const int4*   a4 = (const int4*)(cba + item * 8);
                const float4* w4 = (const float4*)(cbw + item * 8);
                int4 a0 = a4[0], a1 = a4[1];
                float4 wv0 = w4[0], wv1 = w4[1];
                float s = wv0.x * xt[a0.x + lane] + wv0.y * xt[a0.y + lane]
                        + wv0.z * xt[a0.z + lane] + wv0.w * xt[a0.w + lane]
                        + wv1.x * xt[a1.x + lane] + wv1.y * xt[a1.y + lane]
                        + wv1.z * xt[a1.z + lane] + wv1.w * xt[a1.w + lane];
                sb[tl * 64] = f2bf(s);
            }
        }
        __syncthreads();

        // MFMA over this K-chunk (576), split across kh halves
#pragma unroll
        for (int s = 0; s < 9; s++) {
            int k_local = kh * 288 + s * 32;
            int kb = ((g * 576 + k_local) >> 3) + quad;
            short8 afrag = wa8[kb * 32 + mt * 16 + col];
            short8 bfrag = *(const short8*)(smem + col * SST + k_local + quad * 8);
            acc = __builtin_amdgcn_mfma_f32_16x16x32_bf16(afrag, bfrag, acc, 0, 0, 0);
        }
    }
    __syncthreads();        // cb region free -> pbuf

    if (kh == 1) {
#pragma unroll
        for (int r = 0; r < 4; r++) pbuf[mt * 256 + (quad * 4 + r) * 16 + col] = acc[r];
    }
    __syncthreads();
    if (kh == 0) {
#pragma unroll
        for (int r = 0; r < 4; r++) {
            int o = mt * 16 + quad * 4 + r;
            float val = acc[r] + pbuf[mt * 256 + (quad * 4 + r) * 16 + col] + bias[o];
            out[o * NVOX + pbase + col] = val;
            atomicAdd(&rsum[o], val);
            atomicAdd(&rsq[o], val * val);
        }
    }
    __syncthreads();
    if (tid < COUT) {
        atomicAdd(&gstat[tid], rsum[tid]);
        atomicAdd(&gstat[COUT + tid], rsq[tid]);
    }
}

// ---------------------------------------------------------------------------
// BN finalize + ReLU, in-place on d_out.
// ---------------------------------------------------------------------------
__global__ void bn_kernel(const float* __restrict__ ws,
                          const float* __restrict__ gamma,
                          const float* __restrict__ beta,
                          float* out) {
    int i = blockIdx.x * 256 + threadIdx.x;
    int o = i >> 15;
    const float* gstat = ws + WS_STAT;
    const float inv = 1.f / 32768.f;
    float mean = gstat[o] * inv;
    float var  = gstat[COUT + o] * inv - mean * mean;
    float sc   = rsqrtf(var + 1e-5f) * gamma[o];
    float v = (out[i] - mean) * sc + beta[o];
    out[i] = fmaxf(v, 0.f);
}

// ---------------------------------------------------------------------------
extern "C" void kernel_launch(void* const* d_in, const int* in_sizes, int n_in,
                              void* d_out, int out_size, void* d_ws, size_t ws_size,
                              hipStream_t stream) {
    const float* x     = (const float*)d_in[0];
    const float* w_off = (const float*)d_in[1];
    const float* b_off = (const float*)d_in[2];
    const float* wmat  = (const float*)d_in[3];
    const float* bias  = (const float*)d_in[4];
    const float* gamma = (const float*)d_in[5];
    const float* beta  = (const float*)d_in[6];
    float* ws  = (float*)d_ws;
    float* out = (float*)d_out;

    prep_all_kernel<<<5941, 64, 0, stream>>>(x, w_off, wmat, ws);
    deform_kernel<<<2048, 256, 0, stream>>>(b_off, bias, ws, out);
    bn_kernel<<<4096, 256, 0, stream>>>(ws, gamma, beta, out);
}

// Round 9
// 181.368 us; speedup vs baseline: 1.5439x; 1.0962x over previous
//
#include <hip/hip_runtime.h>
#include <math.h>

// Problem constants
#define NVOX  32768     // 32^3 up-res voxels
#define CIN   64
#define COUT  32
#define KT    27
#define CIT   1728      // CIN*KT
#define PSP   5832      // 18^3 padded half-res spatial

// Workspace layout (float offsets)
#define WS_XT   0                 // fp16[5832][64] channel-last padded x
#define WS_WA   186624            // fp16[216][32][8] deform-W A-frags (K tap-major)
#define WS_WO   214272            // fp16[216][96][8] offset-W A-frags (M padded 81->96)
#define WS_STAT 297216            // [32] sum, [32] sumsq

#define SST 584                   // S chunk row stride in u16 (1168 B)

typedef __attribute__((ext_vector_type(8))) _Float16 half8;
typedef __attribute__((ext_vector_type(2))) _Float16 half2v;
typedef __attribute__((ext_vector_type(4))) float floatx4;

static __device__ __forceinline__ unsigned dup16(float w) {
    unsigned short b = __builtin_bit_cast(unsigned short, (_Float16)w);
    return (unsigned)b * 0x10001u;
}
static __device__ __forceinline__ half2v u2h2(unsigned u) {
    return __builtin_bit_cast(half2v, u);
}

// ---------------------------------------------------------------------------
// Merged prep:
//   blocks [0,92):    XT fill via LDS transpose (coalesced read AND write)
//   blocks [92,119):  pack wmat  -> WA fp16 A-frags (K = tap*64+ci)
//   blocks [119,200): pack w_off -> WO fp16 A-frags (M=96, rows 81..95 = 0)
//   block  200:       zero stats
// ---------------------------------------------------------------------------
__global__ void prep_all_kernel(const float* __restrict__ x,
                                const float* __restrict__ w_off,
                                const float* __restrict__ wmat,
                                float* __restrict__ ws) {
    int b = blockIdx.x, t = threadIdx.x;
    if (b < 92) {
        __shared__ _Float16 tile[64][65];
        _Float16* xth = (_Float16*)(ws + WS_XT);
        int base = b * 64;
        int cell = base + t;                    // lane = cell
        int qw = cell % 18, qh = (cell / 18) % 18, qd = cell / 324;
        bool interior = (cell < PSP) && qd >= 1 && qd <= 16 && qh >= 1 && qh <= 16
                        && qw >= 1 && qw <= 16;
        int xbase = interior ? (((qd - 1) * 16 + (qh - 1)) * 16 + (qw - 1)) : 0;
#pragma unroll 8
        for (int c = 0; c < 64; c++) {
            float v = interior ? x[c * 4096 + xbase] : 0.f;
            tile[t][c] = (_Float16)v;
        }
        __syncthreads();
#pragma unroll 8
        for (int s = 0; s < 64; s++) {
            int cell2 = base + s;
            if (cell2 < PSP) xth[cell2 * 64 + t] = tile[s][t];   // lane = channel
        }
    } else if (b < 119) {
        _Float16* wa = (_Float16*)(ws + WS_WA);
        int idx4 = ((b - 92) * 64 + t) * 4;
#pragma unroll
        for (int m = 0; m < 4; m++) {
            int idx = idx4 + m;                 // (kb, o)
            int kb = idx >> 5, o = idx & 31;
#pragma unroll
            for (int j = 0; j < 8; j++) {
                int kk = kb * 8 + j;            // K index, tap-major
                int tap = kk >> 6, ci = kk & 63;
                wa[idx * 8 + j] = (_Float16)wmat[o * CIT + ci * 27 + tap];
            }
        }
    } else if (b < 200) {
        _Float16* wo = (_Float16*)(ws + WS_WO);
        int idx4 = ((b - 119) * 64 + t) * 4;
#pragma unroll
        for (int mm = 0; mm < 4; mm++) {
            int idx = idx4 + mm;                // kb*96 + m
            int kb = idx / 96, m = idx % 96;
#pragma unroll
            for (int j = 0; j < 8; j++) {
                int kk = kb * 8 + j;
                int tap = kk >> 6, ci = kk & 63;
                float v = (m < 81) ? w_off[(m * 64 + ci) * 27 + tap] : 0.f;
                wo[idx * 8 + j] = (_Float16)v;
            }
        }
    } else {
        ws[WS_STAT + t] = 0.f;
    }
}

// ---------------------------------------------------------------------------
// Fused offset-GEMM + deformable sample + deform-GEMM + BN stats, fp16 path.
// Block = 256 threads = 4 waves = 16 voxels.
// Gathers are channel-pair packed: lane = (vsel, cl); dword = 2 fp16 channels;
// half-wave per voxel -> 2 voxels per 8-load batch; v_pk_fma_f16 interp.
// MFMA 16x16x32_f16 (same fragment layout as bf16).
// LDS ~30.8 KB -> 5 blocks/CU.
// ---------------------------------------------------------------------------
__global__ __launch_bounds__(256) void deform_kernel(
        const float* __restrict__ b_off, const float* __restrict__ bias,
        float* ws, float* __restrict__ out) {
    __shared__ __align__(16) unsigned short smem[16 * SST];   // 18688 B
    __shared__ __align__(16) _Float16 Plh[81 * 16];           // 2592 B
    __shared__ __align__(16) char ubuf[9216];
    __shared__ float rsum[COUT], rsq[COUT];

    float*    red  = (float*)ubuf;             // 96*16 f32 (phase0 reduce)
    int*      cba  = (int*)ubuf;               // 144*8 int  (corner h2-indices)
    unsigned* cbw  = (unsigned*)(ubuf + 4608); // 144*8 uint (dup fp16 weights)
    float*    pbuf = (float*)ubuf;             // 512 f32 (epilogue)

    const half2v* xt2 = (const half2v*)(ws + WS_XT);
    const unsigned* xtu = (const unsigned*)(ws + WS_XT);
    const half8* wa8 = (const half8*)(ws + WS_WA);
    const half8* wo8 = (const half8*)(ws + WS_WO);
    float* gstat = ws + WS_STAT;

    int tid = threadIdx.x, wave = tid >> 6, lane = tid & 63;
    int vsel = lane >> 5, cl = lane & 31;
    int pbase = blockIdx.x * 16;
    int d = pbase >> 10, h = (pbase >> 5) & 31, w0 = pbase & 31;

    if (tid < COUT) { rsum[tid] = 0.f; rsq[tid] = 0.f; }

    int mh = wave & 1, kh = wave >> 1;
    int col = lane & 15, quad = lane >> 4;

    // ================= Phase 0: offset GEMM =================
    floatx4 oacc0 = {0.f,0.f,0.f,0.f}, oacc1 = {0.f,0.f,0.f,0.f}, oacc2 = {0.f,0.f,0.f,0.f};
#pragma unroll 1
    for (int g = 0; g < 3; g++) {
        if (g) __syncthreads();             // prior MFMA smem reads done
        int rd = ((d + g - 1) >> 1) + 1;
#pragma unroll
        for (int tl = 0; tl < 9; tl++) {
            int kh2 = tl / 3, kw2 = tl % 3;
            int rh = ((h + kh2 - 1) >> 1) + 1;
#pragma unroll
            for (int pi = 0; pi < 2; pi++) {
                int v = wave * 4 + pi * 2 + vsel;
                int w = w0 + v;
                int rw = ((w + kw2 - 1) >> 1) + 1;
                int cell = (rd * 18 + rh) * 18 + rw;
                unsigned uv = xtu[cell * 32 + cl];
                *(unsigned*)(smem + v * SST + tl * 64 + 2 * cl) = uv;
            }
        }
        __syncthreads();
#pragma unroll
        for (int s = 0; s < 9; s++) {
            int k_local = kh * 288 + s * 32;
            int kb = ((g * 576 + k_local) >> 3) + quad;
            half8 bfrag = *(const half8*)(smem + col * SST + k_local + quad * 8);
            half8 a0 = wo8[kb * 96 + mh * 48 + col];
            half8 a1 = wo8[kb * 96 + mh * 48 + 16 + col];
            half8 a2 = wo8[kb * 96 + mh * 48 + 32 + col];
            oacc0 = __builtin_amdgcn_mfma_f32_16x16x32_f16(a0, bfrag, oacc0, 0, 0, 0);
            oacc1 = __builtin_amdgcn_mfma_f32_16x16x32_f16(a1, bfrag, oacc1, 0, 0, 0);
            oacc2 = __builtin_amdgcn_mfma_f32_16x16x32_f16(a2, bfrag, oacc2, 0, 0, 0);
        }
    }
    __syncthreads();
    if (kh == 1) {
#pragma unroll
        for (int r = 0; r < 4; r++) {
            red[(mh * 48 +      quad * 4 + r) * 16 + col] = oacc0[r];
            red[(mh * 48 + 16 + quad * 4 + r) * 16 + col] = oacc1[r];
            red[(mh * 48 + 32 + quad * 4 + r) * 16 + col] = oacc2[r];
        }
    }
    __syncthreads();
    if (kh == 0) {
#pragma unroll
        for (int r = 0; r < 4; r++) {
            int m0 = mh * 48 + quad * 4 + r;
            Plh[m0 * 16 + col] = (_Float16)(oacc0[r] + red[m0 * 16 + col] + b_off[m0]);
            int m1 = m0 + 16;
            Plh[m1 * 16 + col] = (_Float16)(oacc1[r] + red[m1 * 16 + col] + b_off[m1]);
            int m2 = m0 + 32;
            if (m2 < 81)
                Plh[m2 * 16 + col] = (_Float16)(oacc2[r] + red[m2 * 16 + col] + b_off[m2]);
        }
    }
    // Plh ready after next sync; red then free -> cba/cbw

    // ================= Phase 1: deform sample + GEMM =================
    int mt = wave & 1;
    floatx4 acc = {0.f, 0.f, 0.f, 0.f};

#pragma unroll 1
    for (int g = 0; g < 3; g++) {
        __syncthreads();   // Plh ready (g=0) / prior gather+MFMA reads done
        if (tid < 144) {
            int v = tid & 15, tl = tid >> 4;
            int tap = g * 9 + tl;
            int kh2 = tl / 3, kw2 = tl % 3;
            int w = w0 + v;
            float od = (float)Plh[(3 * tap + 0) * 16 + v];
            float oh = (float)Plh[(3 * tap + 1) * 16 + v];
            float ow = (float)Plh[(3 * tap + 2) * 16 + v];
            float pdc = (float)(d + g - 1) + od;
            float phc = (float)(h + kh2 - 1) + oh;
            float pwc = (float)(w + kw2 - 1) + ow;
            float fd0 = floorf(pdc), fh0 = floorf(phc), fw0 = floorf(pwc);
            float fd = pdc - fd0, fh = phc - fh0, fw = pwc - fw0;
            int id = (int)fd0, ih = (int)fh0, iw = (int)fw0;
            // corner bases in h2 units: cell * 32
            int rd0 = ((min(max(id,     -2), 33) >> 1) + 1) * (324 * 32);
            int rd1 = ((min(max(id + 1, -2), 33) >> 1) + 1) * (324 * 32);
            int rh0 = ((min(max(ih,     -2), 33) >> 1) + 1) * (18 * 32);
            int rh1 = ((min(max(ih + 1, -2), 33) >> 1) + 1) * (18 * 32);
            int rw0 = ((min(max(iw,     -2), 33) >> 1) + 1) * 32;
            int rw1 = ((min(max(iw + 1, -2), 33) >> 1) + 1) * 32;
            int* A = cba + tid * 8;
            unsigned* W = cbw + tid * 8;
            A[0] = rd0 + rh0 + rw0; A[1] = rd0 + rh0 + rw1;
            A[2] = rd0 + rh1 + rw0; A[3] = rd0 + rh1 + rw1;
            A[4] = rd1 + rh0 + rw0; A[5] = rd1 + rh0 + rw1;
            A[6] = rd1 + rh1 + rw0; A[7] = rd1 + rh1 + rw1;
            float gd = 1.f - fd, gh = 1.f - fh, gw = 1.f - fw;
            W[0] = dup16(gd * gh * gw); W[1] = dup16(gd * gh * fw);
            W[2] = dup16(gd * fh * gw); W[3] = dup16(gd * fh * fw);
            W[4] = dup16(fd * gh * gw); W[5] = dup16(fd * gh * fw);
            W[6] = dup16(fd * fh * gw); W[7] = dup16(fd * fh * fw);
        }
        __syncthreads();

        // Gather: packed fp16, half-wave per voxel, 2 voxels per batch
#pragma unroll
        for (int tl = 0; tl < 9; tl++) {
#pragma unroll
            for (int pi = 0; pi < 2; pi++) {
                int v = wave * 4 + pi * 2 + vsel;
                int item = tl * 16 + v;
                const int4* a4 = (const int4*)(cba + item * 8);
                const int4* w4 = (const int4*)(cbw + item * 8);
                int4 A0 = a4[0], A1 = a4[1];
                int4 U0 = w4[0], U1 = w4[1];
                half2v s = u2h2(U0.x) * xt2[A0.x + cl];
                s += u2h2(U0.y) * xt2[A0.y + cl];
                s += u2h2(U0.z) * xt2[A0.z + cl];
                s += u2h2(U0.w) * xt2[A0.w + cl];
                s += u2h2(U1.x) * xt2[A1.x + cl];
                s += u2h2(U1.y) * xt2[A1.y + cl];
                s += u2h2(U1.z) * xt2[A1.z + cl];
                s += u2h2(U1.w) * xt2[A1.w + cl];
                *(unsigned*)(smem + v * SST + tl * 64 + 2 * cl) =
                    __builtin_bit_cast(unsigned, s);
            }
        }
        __syncthreads();

        // MFMA over this K-chunk (576), split across kh halves
#pragma unroll
        for (int s = 0; s < 9; s++) {
            int k_local = kh * 288 + s * 32;
            int kb = ((g * 576 + k_local) >> 3) + quad;
            half8 afrag = wa8[kb * 32 + mt * 16 + col];
            half8 bfrag = *(const half8*)(smem + col * SST + k_local + quad * 8);
            acc = __builtin_amdgcn_mfma_f32_16x16x32_f16(afrag, bfrag, acc, 0, 0, 0);
        }
    }
    __syncthreads();        // cb region free -> pbuf

    if (kh == 1) {
#pragma unroll
        for (int r = 0; r < 4; r++) pbuf[mt * 256 + (quad * 4 + r) * 16 + col] = acc[r];
    }
    __syncthreads();
    if (kh == 0) {
#pragma unroll
        for (int r = 0; r < 4; r++) {
            int o = mt * 16 + quad * 4 + r;
            float val = acc[r] + pbuf[mt * 256 + (quad * 4 + r) * 16 + col] + bias[o];
            out[o * NVOX + pbase + col] = val;
            atomicAdd(&rsum[o], val);
            atomicAdd(&rsq[o], val * val);
        }
    }
    __syncthreads();
    if (tid < COUT) {
        atomicAdd(&gstat[tid], rsum[tid]);
        atomicAdd(&gstat[COUT + tid], rsq[tid]);
    }
}

// ---------------------------------------------------------------------------
// BN finalize + ReLU, in-place on d_out.
// ---------------------------------------------------------------------------
__global__ void bn_kernel(const float* __restrict__ ws,
                          const float* __restrict__ gamma,
                          const float* __restrict__ beta,
                          float* out) {
    int i = blockIdx.x * 256 + threadIdx.x;
    int o = i >> 15;
    const float* gstat = ws + WS_STAT;
    const float inv = 1.f / 32768.f;
    float mean = gstat[o] * inv;
    float var  = gstat[COUT + o] * inv - mean * mean;
    float sc   = rsqrtf(var + 1e-5f) * gamma[o];
    float v = (out[i] - mean) * sc + beta[o];
    out[i] = fmaxf(v, 0.f);
}

// ---------------------------------------------------------------------------
extern "C" void kernel_launch(void* const* d_in, const int* in_sizes, int n_in,
                              void* d_out, int out_size, void* d_ws, size_t ws_size,
                              hipStream_t stream) {
    const float* x     = (const float*)d_in[0];
    const float* w_off = (const float*)d_in[1];
    const float* b_off = (const float*)d_in[2];
    const float* wmat  = (const float*)d_in[3];
    const float* bias  = (const float*)d_in[4];
    const float* gamma = (const float*)d_in[5];
    const float* beta  = (const float*)d_in[6];
    float* ws  = (float*)d_ws;
    float* out = (float*)d_out;

    prep_all_kernel<<<201, 64, 0, stream>>>(x, w_off, wmat, ws);
    deform_kernel<<<2048, 256, 0, stream>>>(b_off, bias, ws, out);
    bn_kernel<<<4096, 256, 0, stream>>>(ws, gamma, beta, out);
}

// Round 10
// 166.261 us; speedup vs baseline: 1.6842x; 1.0909x over previous
//
#include <hip/hip_runtime.h>
#include <math.h>

// Problem constants
#define NVOX  32768     // 32^3 up-res voxels
#define CIN   64
#define COUT  32
#define KT    27
#define CIT   1728      // CIN*KT
#define PSP   5832      // 18^3 padded half-res spatial

// Workspace layout (float offsets)
#define WS_XT   0                 // fp16[5832][64] channel-last padded x
#define WS_WA   186624            // fp16[216][32][8] deform-W A-frags (K tap-major)
#define WS_WO   214272            // fp16[216][96][8] offset-W A-frags (M padded 81->96)
#define WS_STAT 297216            // [32] sum, [32] sumsq

#define SST 584                   // S chunk row stride in u16 (1168 B)

typedef __attribute__((ext_vector_type(8))) _Float16 half8;
typedef __attribute__((ext_vector_type(2))) _Float16 half2v;
typedef __attribute__((ext_vector_type(4))) float floatx4;

static __device__ __forceinline__ unsigned dup16(float w) {
    unsigned short b = __builtin_bit_cast(unsigned short, (_Float16)w);
    return (unsigned)b * 0x10001u;
}
static __device__ __forceinline__ half2v u2h2(unsigned u) {
    return __builtin_bit_cast(half2v, u);
}

// ---------------------------------------------------------------------------
// Merged prep, 256-thread blocks, ILP-covered latency:
//   blocks [0,92):    XT fill via LDS transpose; thread=(chan-quarter, cell),
//                     16 independent loads + 16 coalesced stores each
//   blocks [92,119):  pack wmat  -> WA; thread = one (kb,o) row: 8 loads+16B st
//   blocks [119,200): pack w_off -> WO; thread = one (kb,m) row: 8 loads+16B st
//   block  200:       zero stats
// ---------------------------------------------------------------------------
__global__ __launch_bounds__(256) void prep_all_kernel(
        const float* __restrict__ x, const float* __restrict__ w_off,
        const float* __restrict__ wmat, float* __restrict__ ws) {
    int b = blockIdx.x, t = threadIdx.x;
    if (b < 92) {
        __shared__ _Float16 tile[64][65];
        _Float16* xth = (_Float16*)(ws + WS_XT);
        int tq = t >> 6, lane = t & 63;
        int base = b * 64;
        int cell = base + lane;                 // lane = cell (read side)
        int qw = cell % 18, qh = (cell / 18) % 18, qd = cell / 324;
        bool interior = (cell < PSP) && qd >= 1 && qd <= 16 && qh >= 1 && qh <= 16
                        && qw >= 1 && qw <= 16;
        int xbase = interior ? (((qd - 1) * 16 + (qh - 1)) * 16 + (qw - 1)) : 0;
#pragma unroll
        for (int i = 0; i < 16; i++) {
            int c = tq * 16 + i;
            float v = interior ? x[c * 4096 + xbase] : 0.f;
            tile[lane][c] = (_Float16)v;
        }
        __syncthreads();
#pragma unroll
        for (int i = 0; i < 16; i++) {
            int s = tq * 16 + i;
            int cell2 = base + s;
            if (cell2 < PSP) xth[cell2 * 64 + lane] = tile[s][lane];  // lane = chan
        }
    } else if (b < 119) {
        _Float16* wa = (_Float16*)(ws + WS_WA);
        int idx = (b - 92) * 256 + t;           // 0..6911  (kb, o)
        int kb = idx >> 5, o = idx & 31;
        half8 r;
#pragma unroll
        for (int j = 0; j < 8; j++) {
            int kk = kb * 8 + j;                // K index, tap-major
            int tap = kk >> 6, ci = kk & 63;
            r[j] = (_Float16)wmat[o * CIT + ci * 27 + tap];
        }
        *(half8*)(wa + idx * 8) = r;
    } else if (b < 200) {
        _Float16* wo = (_Float16*)(ws + WS_WO);
        int idx = (b - 119) * 256 + t;          // 0..20735 = kb*96 + m
        int kb = idx / 96, m = idx % 96;
        half8 r;
#pragma unroll
        for (int j = 0; j < 8; j++) {
            int kk = kb * 8 + j;
            int tap = kk >> 6, ci = kk & 63;
            float v = (m < 81) ? w_off[(m * 64 + ci) * 27 + tap] : 0.f;
            r[j] = (_Float16)v;
        }
        *(half8*)(wo + idx * 8) = r;
    } else {
        if (t < 64) ws[WS_STAT + t] = 0.f;
    }
}

// ---------------------------------------------------------------------------
// Fused offset-GEMM + deformable sample + deform-GEMM + BN stats, fp16 path.
// (unchanged from R9: VGPR 60, LDS 30.8 KB, 5 blocks/CU)
// ---------------------------------------------------------------------------
__global__ __launch_bounds__(256) void deform_kernel(
        const float* __restrict__ b_off, const float* __restrict__ bias,
        float* ws, float* __restrict__ out) {
    __shared__ __align__(16) unsigned short smem[16 * SST];   // 18688 B
    __shared__ __align__(16) _Float16 Plh[81 * 16];           // 2592 B
    __shared__ __align__(16) char ubuf[9216];
    __shared__ float rsum[COUT], rsq[COUT];

    float*    red  = (float*)ubuf;             // 96*16 f32 (phase0 reduce)
    int*      cba  = (int*)ubuf;               // 144*8 int  (corner h2-indices)
    unsigned* cbw  = (unsigned*)(ubuf + 4608); // 144*8 uint (dup fp16 weights)
    float*    pbuf = (float*)ubuf;             // 512 f32 (epilogue)

    const half2v* xt2 = (const half2v*)(ws + WS_XT);
    const unsigned* xtu = (const unsigned*)(ws + WS_XT);
    const half8* wa8 = (const half8*)(ws + WS_WA);
    const half8* wo8 = (const half8*)(ws + WS_WO);
    float* gstat = ws + WS_STAT;

    int tid = threadIdx.x, wave = tid >> 6, lane = tid & 63;
    int vsel = lane >> 5, cl = lane & 31;
    int pbase = blockIdx.x * 16;
    int d = pbase >> 10, h = (pbase >> 5) & 31, w0 = pbase & 31;

    if (tid < COUT) { rsum[tid] = 0.f; rsq[tid] = 0.f; }

    int mh = wave & 1, kh = wave >> 1;
    int col = lane & 15, quad = lane >> 4;

    // ================= Phase 0: offset GEMM =================
    floatx4 oacc0 = {0.f,0.f,0.f,0.f}, oacc1 = {0.f,0.f,0.f,0.f}, oacc2 = {0.f,0.f,0.f,0.f};
#pragma unroll 1
    for (int g = 0; g < 3; g++) {
        if (g) __syncthreads();             // prior MFMA smem reads done
        int rd = ((d + g - 1) >> 1) + 1;
#pragma unroll
        for (int tl = 0; tl < 9; tl++) {
            int kh2 = tl / 3, kw2 = tl % 3;
            int rh = ((h + kh2 - 1) >> 1) + 1;
#pragma unroll
            for (int pi = 0; pi < 2; pi++) {
                int v = wave * 4 + pi * 2 + vsel;
                int w = w0 + v;
                int rw = ((w + kw2 - 1) >> 1) + 1;
                int cell = (rd * 18 + rh) * 18 + rw;
                unsigned uv = xtu[cell * 32 + cl];
                *(unsigned*)(smem + v * SST + tl * 64 + 2 * cl) = uv;
            }
        }
        __syncthreads();
#pragma unroll
        for (int s = 0; s < 9; s++) {
            int k_local = kh * 288 + s * 32;
            int kb = ((g * 576 + k_local) >> 3) + quad;
            half8 bfrag = *(const half8*)(smem + col * SST + k_local + quad * 8);
            half8 a0 = wo8[kb * 96 + mh * 48 + col];
            half8 a1 = wo8[kb * 96 + mh * 48 + 16 + col];
            half8 a2 = wo8[kb * 96 + mh * 48 + 32 + col];
            oacc0 = __builtin_amdgcn_mfma_f32_16x16x32_f16(a0, bfrag, oacc0, 0, 0, 0);
            oacc1 = __builtin_amdgcn_mfma_f32_16x16x32_f16(a1, bfrag, oacc1, 0, 0, 0);
            oacc2 = __builtin_amdgcn_mfma_f32_16x16x32_f16(a2, bfrag, oacc2, 0, 0, 0);
        }
    }
    __syncthreads();
    if (kh == 1) {
#pragma unroll
        for (int r = 0; r < 4; r++) {
            red[(mh * 48 +      quad * 4 + r) * 16 + col] = oacc0[r];
            red[(mh * 48 + 16 + quad * 4 + r) * 16 + col] = oacc1[r];
            red[(mh * 48 + 32 + quad * 4 + r) * 16 + col] = oacc2[r];
        }
    }
    __syncthreads();
    if (kh == 0) {
#pragma unroll
        for (int r = 0; r < 4; r++) {
            int m0 = mh * 48 + quad * 4 + r;
            Plh[m0 * 16 + col] = (_Float16)(oacc0[r] + red[m0 * 16 + col] + b_off[m0]);
            int m1 = m0 + 16;
            Plh[m1 * 16 + col] = (_Float16)(oacc1[r] + red[m1 * 16 + col] + b_off[m1]);
            int m2 = m0 + 32;
            if (m2 < 81)
                Plh[m2 * 16 + col] = (_Float16)(oacc2[r] + red[m2 * 16 + col] + b_off[m2]);
        }
    }
    // Plh ready after next sync; red then free -> cba/cbw

    // ================= Phase 1: deform sample + GEMM =================
    int mt = wave & 1;
    floatx4 acc = {0.f, 0.f, 0.f, 0.f};

#pragma unroll 1
    for (int g = 0; g < 3; g++) {
        __syncthreads();   // Plh ready (g=0) / prior gather+MFMA reads done
        if (tid < 144) {
            int v = tid & 15, tl = tid >> 4;
            int tap = g * 9 + tl;
            int kh2 = tl / 3, kw2 = tl % 3;
            int w = w0 + v;
            float od = (float)Plh[(3 * tap + 0) * 16 + v];
            float oh = (float)Plh[(3 * tap + 1) * 16 + v];
            float ow = (float)Plh[(3 * tap + 2) * 16 + v];
            float pdc = (float)(d + g - 1) + od;
            float phc = (float)(h + kh2 - 1) + oh;
            float pwc = (float)(w + kw2 - 1) + ow;
            float fd0 = floorf(pdc), fh0 = floorf(phc), fw0 = floorf(pwc);
            float fd = pdc - fd0, fh = phc - fh0, fw = pwc - fw0;
            int id = (int)fd0, ih = (int)fh0, iw = (int)fw0;
            // corner bases in h2 units: cell * 32
            int rd0 = ((min(max(id,     -2), 33) >> 1) + 1) * (324 * 32);
            int rd1 = ((min(max(id + 1, -2), 33) >> 1) + 1) * (324 * 32);
            int rh0 = ((min(max(ih,     -2), 33) >> 1) + 1) * (18 * 32);
            int rh1 = ((min(max(ih + 1, -2), 33) >> 1) + 1) * (18 * 32);
            int rw0 = ((min(max(iw,     -2), 33) >> 1) + 1) * 32;
            int rw1 = ((min(max(iw + 1, -2), 33) >> 1) + 1) * 32;
            int* A = cba + tid * 8;
            unsigned* W = cbw + tid * 8;
            A[0] = rd0 + rh0 + rw0; A[1] = rd0 + rh0 + rw1;
            A[2] = rd0 + rh1 + rw0; A[3] = rd0 + rh1 + rw1;
            A[4] = rd1 + rh0 + rw0; A[5] = rd1 + rh0 + rw1;
            A[6] = rd1 + rh1 + rw0; A[7] = rd1 + rh1 + rw1;
            float gd = 1.f - fd, gh = 1.f - fh, gw = 1.f - fw;
            W[0] = dup16(gd * gh * gw); W[1] = dup16(gd * gh * fw);
            W[2] = dup16(gd * fh * gw); W[3] = dup16(gd * fh * fw);
            W[4] = dup16(fd * gh * gw); W[5] = dup16(fd * gh * fw);
            W[6] = dup16(fd * fh * gw); W[7] = dup16(fd * fh * fw);
        }
        __syncthreads();

        // Gather: packed fp16, half-wave per voxel, 2 voxels per batch
#pragma unroll
        for (int tl = 0; tl < 9; tl++) {
#pragma unroll
            for (int pi = 0; pi < 2; pi++) {
                int v = wave * 4 + pi * 2 + vsel;
                int item = tl * 16 + v;
                const int4* a4 = (const int4*)(cba + item * 8);
                const int4* w4 = (const int4*)(cbw + item * 8);
                int4 A0 = a4[0], A1 = a4[1];
                int4 U0 = w4[0], U1 = w4[1];
                half2v s = u2h2(U0.x) * xt2[A0.x + cl];
                s += u2h2(U0.y) * xt2[A0.y + cl];
                s += u2h2(U0.z) * xt2[A0.z + cl];
                s += u2h2(U0.w) * xt2[A0.w + cl];
                s += u2h2(U1.x) * xt2[A1.x + cl];
                s += u2h2(U1.y) * xt2[A1.y + cl];
                s += u2h2(U1.z) * xt2[A1.z + cl];
                s += u2h2(U1.w) * xt2[A1.w + cl];
                *(unsigned*)(smem + v * SST + tl * 64 + 2 * cl) =
                    __builtin_bit_cast(unsigned, s);
            }
        }
        __syncthreads();

        // MFMA over this K-chunk (576), split across kh halves
#pragma unroll
        for (int s = 0; s < 9; s++) {
            int k_local = kh * 288 + s * 32;
            int kb = ((g * 576 + k_local) >> 3) + quad;
            half8 afrag = wa8[kb * 32 + mt * 16 + col];
            half8 bfrag = *(const half8*)(smem + col * SST + k_local + quad * 8);
            acc = __builtin_amdgcn_mfma_f32_16x16x32_f16(afrag, bfrag, acc, 0, 0, 0);
        }
    }
    __syncthreads();        // cb region free -> pbuf

    if (kh == 1) {
#pragma unroll
        for (int r = 0; r < 4; r++) pbuf[mt * 256 + (quad * 4 + r) * 16 + col] = acc[r];
    }
    __syncthreads();
    if (kh == 0) {
#pragma unroll
        for (int r = 0; r < 4; r++) {
            int o = mt * 16 + quad * 4 + r;
            float val = acc[r] + pbuf[mt * 256 + (quad * 4 + r) * 16 + col] + bias[o];
            out[o * NVOX + pbase + col] = val;
            atomicAdd(&rsum[o], val);
            atomicAdd(&rsq[o], val * val);
        }
    }
    __syncthreads();
    if (tid < COUT) {
        atomicAdd(&gstat[tid], rsum[tid]);
        atomicAdd(&gstat[COUT + tid], rsq[tid]);
    }
}

// ---------------------------------------------------------------------------
// BN finalize + ReLU, in-place on d_out.
// ---------------------------------------------------------------------------
__global__ void bn_kernel(const float* __restrict__ ws,
                          const float* __restrict__ gamma,
                          const float* __restrict__ beta,
                          float* out) {
    int i = blockIdx.x * 256 + threadIdx.x;
    int o = i >> 15;
    const float* gstat = ws + WS_STAT;
    const float inv = 1.f / 32768.f;
    float mean = gstat[o] * inv;
    float var  = gstat[COUT + o] * inv - mean * mean;
    float sc   = rsqrtf(var + 1e-5f) * gamma[o];
    float v = (out[i] - mean) * sc + beta[o];
    out[i] = fmaxf(v, 0.f);
}

// ---------------------------------------------------------------------------
extern "C" void kernel_launch(void* const* d_in, const int* in_sizes, int n_in,
                              void* d_out, int out_size, void* d_ws, size_t ws_size,
                              hipStream_t stream) {
    const float* x     = (const float*)d_in[0];
    const float* w_off = (const float*)d_in[1];
    const float* b_off = (const float*)d_in[2];
    const float* wmat  = (const float*)d_in[3];
    const float* bias  = (const float*)d_in[4];
    const float* gamma = (const float*)d_in[5];
    const float* beta  = (const float*)d_in[6];
    float* ws  = (float*)d_ws;
    float* out = (float*)d_out;

    prep_all_kernel<<<201, 256, 0, stream>>>(x, w_off, wmat, ws);
    deform_kernel<<<2048, 256, 0, stream>>>(b_off, bias, ws, out);
    bn_kernel<<<4096, 256, 0, stream>>>(ws, gamma, beta, out);
}